// Round 6
// baseline (339.978 us; speedup 1.0000x reference)
//
#include <hip/hip_runtime.h>

#define NN 50000
#define NE 800000
#define NB 196   // (NN+255)/256
#define K1B 782  // (NN+63)/64

typedef __attribute__((ext_vector_type(8))) short bf16x8;
typedef __attribute__((ext_vector_type(4))) float f32x4;
typedef __attribute__((ext_vector_type(2))) _Float16 h2f;

__device__ __forceinline__ int rfl(int v) { return __builtin_amdgcn_readfirstlane(v); }

__device__ __forceinline__ unsigned short bfb(float x) {
    union { float f; unsigned u; } v; v.f = x;
    unsigned r = v.u + 0x7FFFu + ((v.u >> 16) & 1u);
    return (unsigned short)(r >> 16);
}
__device__ __forceinline__ unsigned pkbf(float lo, float hi) {
    return ((unsigned)bfb(hi) << 16) | (unsigned)bfb(lo);
}
__device__ __forceinline__ unsigned pkh2(float a, float b) {
    union { h2f h; unsigned u; } x;
    x.h.x = (_Float16)a; x.h.y = (_Float16)b;
    return x.u;
}
__device__ __forceinline__ float fdot2u(unsigned a, unsigned b, float c) {
    union { unsigned u; h2f h; } ua, ub; ua.u = a; ub.u = b;
    return __builtin_amdgcn_fdot2(ua.h, ub.h, c, false);
}

// 16-lane sum, xor DPP pattern (round-2 summation order, absmax 0.03125).
__device__ __forceinline__ float dpp_reduce16(float p) {
    int t;
    t = __builtin_amdgcn_update_dpp(0, __float_as_int(p), 0xB1, 0xF, 0xF, false);
    p += __int_as_float(t);
    t = __builtin_amdgcn_update_dpp(0, __float_as_int(p), 0x4E, 0xF, 0xF, false);
    p += __int_as_float(t);
    t = __builtin_amdgcn_update_dpp(0, __float_as_int(p), 0x124, 0xF, 0xF, false);
    p += __int_as_float(t);
    t = __builtin_amdgcn_update_dpp(0, __float_as_int(p), 0x128, 0xF, 0xF, false);
    p += __int_as_float(t);
    return p;
}

// 2^x via single v_exp_f32 (input pre-scaled by log2(e) upstream).
__device__ __forceinline__ float exp2_hw(float x) {
    float r;
    asm("v_exp_f32 %0, %1" : "=v"(r) : "v"(x));
    return r;
}

// ---------------------------------------------------------------------------
// K0 (tiny prep): bf16-transpose all weights, f16-pair W_e, zero deg, and
// statically set row_start[NN]=NE.
// ---------------------------------------------------------------------------
__global__ __launch_bounds__(256) void k0_prep(
    const float* __restrict__ W_l, const float* __restrict__ W_r,
    const float* __restrict__ res_W, const float* __restrict__ W0,
    const float* __restrict__ W1, const float* __restrict__ W_e,
    unsigned short* __restrict__ Wtl, unsigned short* __restrict__ Wtr,
    unsigned short* __restrict__ Wtres, unsigned short* __restrict__ Wt0,
    unsigned short* __restrict__ Wt1,
    unsigned* __restrict__ Wep,
    int* __restrict__ deg, int* __restrict__ row_start)
{
    const int t0 = blockIdx.x * 256 + threadIdx.x;
    if (t0 < 24576) { int n = t0 / 192, k = t0 - n * 192; Wt0[t0] = bfb(W0[k * 128 + n]); }
    if (t0 < 16384) { int n = t0 >> 7, k = t0 & 127; Wt1[t0] = bfb(W1[k * 128 + n]); }
    if (t0 < 8192) {
        int n = t0 >> 6, k = t0 & 63;
        Wtl[t0]   = bfb(W_l[k * 128 + n]);
        Wtr[t0]   = bfb(W_r[k * 128 + n]);
        Wtres[t0] = bfb(res_W[k * 128 + n]);
    }
    if (t0 < 1024) {  // Wep[c][j] = (W_e[2j][c], W_e[2j+1][c])
        int c = t0 >> 3, j = t0 & 7;
        Wep[t0] = pkh2(W_e[(2 * j) * 128 + c], W_e[(2 * j + 1) * 128 + c]);
    }
    if (t0 < NN) deg[t0] = 0;
    if (t0 == 0) row_start[NN] = NE;
}

// ---------------------------------------------------------------------------
// KA (fused): blocks [0,K1B) do the MFMA node transforms (x_l, x_r -> packed
// f16); blocks [K1B, ...) do degree count + per-edge rank AND pack this
// edge's features f32->f16 (overlaps under the random-atomic latency).
// (ident/res GEMM moved into k6, which already has nf in LDS.)
// ---------------------------------------------------------------------------
__global__ __launch_bounds__(256, 4) void ka_nodes_degree(
    const float* __restrict__ nf,
    const unsigned short* __restrict__ Wtl, const float* __restrict__ b_l,
    const unsigned short* __restrict__ Wtr, const float* __restrict__ b_r,
    unsigned* __restrict__ xlp, unsigned* __restrict__ xrp,
    const int* __restrict__ eidx, int* __restrict__ deg, int* __restrict__ rank,
    const float* __restrict__ ef, unsigned* __restrict__ efp)
{
    if (blockIdx.x >= K1B) {
        int e = (blockIdx.x - K1B) * 256 + threadIdx.x;
        if (e < NE) {
            rank[e] = atomicAdd(deg + eidx[NE + e], 1);
            const float4* er = (const float4*)(ef + (size_t)e * 16);
            float4 v0 = er[0], v1 = er[1], v2 = er[2], v3 = er[3];
            uint4 o0, o1;
            o0.x = pkh2(v0.x, v0.y); o0.y = pkh2(v0.z, v0.w);
            o0.z = pkh2(v1.x, v1.y); o0.w = pkh2(v1.z, v1.w);
            o1.x = pkh2(v2.x, v2.y); o1.y = pkh2(v2.z, v2.w);
            o1.z = pkh2(v3.x, v3.y); o1.w = pkh2(v3.z, v3.w);
            *(uint4*)(efp + (size_t)e * 8)     = o0;
            *(uint4*)(efp + (size_t)e * 8 + 4) = o1;
        }
        return;
    }
    __shared__ __align__(16) unsigned As32[64 * 36];
    const int tid = threadIdx.x;
    const int node0 = blockIdx.x * 64;

    for (int i = tid; i < 64 * 32; i += 256) {
        int n = i >> 5, c2 = i & 31;
        int gn = node0 + n;
        float2 v = make_float2(0.f, 0.f);
        if (gn < NN) v = *(const float2*)(nf + gn * 64 + 2 * c2);
        As32[n * 36 + c2] = pkbf(v.x, v.y);
    }
    __syncthreads();

    const int lane = tid & 63, w = tid >> 6;
    const int c = lane & 15, ko = lane >> 4;
    const unsigned short* As = (const unsigned short*)As32;
    bf16x8 a0 = *(const bf16x8*)(As + (w * 16 + c) * 72 + 0 * 32 + ko * 8);
    bf16x8 a1 = *(const bf16x8*)(As + (w * 16 + c) * 72 + 1 * 32 + ko * 8);
    const int lrow0 = node0 + w * 16 + 4 * ko;

    #pragma unroll
    for (int p = 0; p < 2; ++p) {
        const unsigned short* Wt = (p == 0) ? Wtl : Wtr;
        const float* bias = (p == 0) ? b_l : b_r;
        unsigned* outp = (p == 0) ? xlp : xrp;
        f32x4 acc[8];
        #pragma unroll
        for (int nt = 0; nt < 8; ++nt) acc[nt] = f32x4{0.f, 0.f, 0.f, 0.f};
        #pragma unroll
        for (int nt = 0; nt < 8; ++nt) {
            bf16x8 bf0 = *(const bf16x8*)(Wt + (nt * 16 + c) * 64 + 0 * 32 + ko * 8);
            acc[nt] = __builtin_amdgcn_mfma_f32_16x16x32_bf16(a0, bf0, acc[nt], 0, 0, 0);
            bf16x8 bf1 = *(const bf16x8*)(Wt + (nt * 16 + c) * 64 + 1 * 32 + ko * 8);
            acc[nt] = __builtin_amdgcn_mfma_f32_16x16x32_bf16(a1, bf1, acc[nt], 0, 0, 0);
        }
        // pack channel pairs (2k, 2k+1) to f16x2; partner lives in lane^1.
        float bv[8];
        #pragma unroll
        for (int nt = 0; nt < 8; ++nt) bv[nt] = bias[nt * 16 + c];
        #pragma unroll
        for (int reg = 0; reg < 4; ++reg) {
            int row = lrow0 + reg;
            #pragma unroll
            for (int nt = 0; nt < 8; ++nt) {
                float v = acc[nt][reg] + bv[nt];
                float v2 = __shfl_xor(v, 1, 64);
                if (row < NN && (lane & 1) == 0)
                    outp[row * 64 + nt * 8 + (c >> 1)] = pkh2(v, v2);
            }
        }
    }
}

// ---------------------------------------------------------------------------
// K3a: per-block degree sums.
// ---------------------------------------------------------------------------
__global__ __launch_bounds__(256) void k3a_blocksum(
    const int* __restrict__ deg, int* __restrict__ bsum)
{
    __shared__ int ws[4];
    int i = blockIdx.x * 256 + threadIdx.x;
    int v = (i < NN) ? deg[i] : 0;
    #pragma unroll
    for (int m = 32; m >= 1; m >>= 1) v += __shfl_xor(v, m, 64);
    if ((threadIdx.x & 63) == 0) ws[threadIdx.x >> 6] = v;
    __syncthreads();
    if (threadIdx.x == 0) bsum[blockIdx.x] = ws[0] + ws[1] + ws[2] + ws[3];
}

// ---------------------------------------------------------------------------
// K3c: block-local scan + prefix of bsum -> row_start.
// ---------------------------------------------------------------------------
__global__ __launch_bounds__(256) void k3c_apply(
    const int* __restrict__ deg, const int* __restrict__ bsum,
    int* __restrict__ row_start)
{
    __shared__ int wsum[4];
    __shared__ int roff[4];
    const int tid = threadIdx.x, lane = tid & 63, wid = tid >> 6;
    int bv = (tid < blockIdx.x) ? bsum[tid] : 0;   // blockIdx.x <= 195 < 256
    #pragma unroll
    for (int m = 32; m >= 1; m >>= 1) bv += __shfl_xor(bv, m, 64);
    if (lane == 0) roff[wid] = bv;

    int i = blockIdx.x * 256 + tid;
    int v = (i < NN) ? deg[i] : 0;
    int sc = v;
    #pragma unroll
    for (int m = 1; m < 64; m <<= 1) {
        int t = __shfl_up(sc, m, 64);
        if (lane >= m) sc += t;
    }
    if (lane == 63) wsum[wid] = sc;
    __syncthreads();
    int off = roff[0] + roff[1] + roff[2] + roff[3];
    for (int w = 0; w < wid; ++w) off += wsum[w];
    int excl = off + sc - v;
    if (i < NN) row_start[i] = excl;
}

// ---------------------------------------------------------------------------
// K4: pure scatter (no atomics): pos = row_start[dst] + rank[e].
// ---------------------------------------------------------------------------
__global__ __launch_bounds__(256) void k4_scatter(
    const int* __restrict__ eidx, const int* __restrict__ row_start,
    const int* __restrict__ rank, int2* __restrict__ csr_es)
{
    int e = blockIdx.x * 256 + threadIdx.x;
    if (e >= NE) return;
    int dst = eidx[NE + e];
    csr_es[row_start[dst] + rank[e]] = make_int2(e, eidx[e]);
}

// ---------------------------------------------------------------------------
// K5: fused GATv2 attention + aggregation. One wave per node.
// Chunked CSR preload + readlane (SGPR eid/src, scalar-side ef loads).
// Depth-6 rotating pipeline. exp via v_exp_f32 (att pre-scaled by log2 e).
// x_r read as packed f16; gat_out written as packed bf16 (identical to the
// conversion k6 was doing anyway).
// ---------------------------------------------------------------------------
__global__ __launch_bounds__(256, 4) void k5_attn_aggregate(
    const int2* __restrict__ csr_es, const int* __restrict__ row_start,
    const unsigned* __restrict__ efp, const unsigned* __restrict__ Wep,
    const float* __restrict__ att,
    const unsigned* __restrict__ xlp, const unsigned* __restrict__ xrp,
    const float* __restrict__ gat_bias,
    unsigned* __restrict__ gatp)
{
    const int lane = threadIdx.x & 63;
    const int node = (blockIdx.x * 256 + threadIdx.x) >> 6;
    if (node >= NN) return;
    const int c = lane * 2;

    uint4 t0 = *(const uint4*)(Wep + c * 8);
    uint4 t1 = *(const uint4*)(Wep + c * 8 + 4);
    uint4 t2 = *(const uint4*)(Wep + (c + 1) * 8);
    uint4 t3 = *(const uint4*)(Wep + (c + 1) * 8 + 4);
    unsigned wx0 = t0.x, wx1 = t0.y, wx2 = t0.z, wx3 = t0.w;
    unsigned wx4 = t1.x, wx5 = t1.y, wx6 = t1.z, wx7 = t1.w;
    unsigned wy0 = t2.x, wy1 = t2.y, wy2 = t2.z, wy3 = t2.w;
    unsigned wy4 = t3.x, wy5 = t3.y, wy6 = t3.z, wy7 = t3.w;

    const float LOG2E = 1.44269504088896340736f;
    float2 a2 = *(const float2*)(att + c);
    a2.x *= LOG2E; a2.y *= LOG2E;
    float2 xr;
    {
        union { unsigned u; h2f h; } uxr;
        uxr.u = xrp[node * 64 + lane];
        xr.x = (float)uxr.h.x; xr.y = (float)uxr.h.y;
    }
    const uint4* __restrict__ efq = (const uint4*)efp;
    const unsigned* __restrict__ xlc = xlp + lane;

    const int sj  = rfl(row_start[node]);
    const int epj = rfl(row_start[node + 1]);

    float den = 0.f, n0 = 0.f, n1 = 0.f;

    for (int base = sj; base < epj; base += 64) {
        const int cnt = min(64, epj - base);
        int pidx = base + lane; if (pidx > NE - 1) pidx = NE - 1;
        const int2 mc = csr_es[pidx];   // coalesced: this chunk's (eid, src)

        uint4 aE0, aE1, bE0, bE1, cE0, cE1, dE0, dE1, eE0, eE1, fE0, fE1;
        unsigned aX, bX, cX, dX, eX, fX;

#define LOADS(E0_, E1_, X_, K_)                                            \
        { int kk = (K_); if (kk >= cnt) kk = cnt - 1;                      \
          int eid  = __builtin_amdgcn_readlane(mc.x, kk);                  \
          int srcn = __builtin_amdgcn_readlane(mc.y, kk);                  \
          E0_ = efq[eid * 2 + 0]; E1_ = efq[eid * 2 + 1];                  \
          X_  = xlc[srcn * 64]; }

#define CONSUME(E0_, E1_, X_)                                              \
        { asm volatile("" : "+v"(wx0), "+v"(wx1), "+v"(wx2), "+v"(wx3),    \
                            "+v"(wx4), "+v"(wx5), "+v"(wx6), "+v"(wx7));   \
          asm volatile("" : "+v"(wy0), "+v"(wy1), "+v"(wy2), "+v"(wy3),    \
                            "+v"(wy4), "+v"(wy5), "+v"(wy6), "+v"(wy7));   \
          union { unsigned u; h2f h; } ux; ux.u = (X_);                    \
          float cx0 = (float)ux.h.x, cx1 = (float)ux.h.y;                  \
          float ax = cx0 + xr.x;                                           \
          float ay = cx1 + xr.y;                                           \
          float bx = 0.f, by = 0.f;                                        \
          ax = fdot2u((E0_).x, wx0, ax);  ay = fdot2u((E0_).x, wy0, ay);   \
          bx = fdot2u((E0_).y, wx1, bx);  by = fdot2u((E0_).y, wy1, by);   \
          ax = fdot2u((E0_).z, wx2, ax);  ay = fdot2u((E0_).z, wy2, ay);   \
          bx = fdot2u((E0_).w, wx3, bx);  by = fdot2u((E0_).w, wy3, by);   \
          ax = fdot2u((E1_).x, wx4, ax);  ay = fdot2u((E1_).x, wy4, ay);   \
          bx = fdot2u((E1_).y, wx5, bx);  by = fdot2u((E1_).y, wy5, by);   \
          ax = fdot2u((E1_).z, wx6, ax);  ay = fdot2u((E1_).z, wy6, ay);   \
          bx = fdot2u((E1_).w, wx7, bx);  by = fdot2u((E1_).w, wy7, by);   \
          float evx = ax + bx;                                             \
          float evy = ay + by;                                             \
          float lx = fmaxf(evx, 0.2f * evx);                               \
          float ly = fmaxf(evy, 0.2f * evy);                               \
          float p = lx * a2.x + ly * a2.y;                                 \
          p = dpp_reduce16(p);                                             \
          float ev = exp2_hw(p);                                           \
          den += ev; n0 += ev * cx0; n1 += ev * cx1; }

        LOADS(aE0, aE1, aX, 0);
        LOADS(bE0, bE1, bX, 1);
        LOADS(cE0, cE1, cX, 2);
        LOADS(dE0, dE1, dX, 3);
        LOADS(eE0, eE1, eX, 4);
        int j = 0;
        while (j + 6 <= cnt) {
            LOADS(fE0, fE1, fX, j + 5);
            CONSUME(aE0, aE1, aX);
            LOADS(aE0, aE1, aX, j + 6);
            CONSUME(bE0, bE1, bX);
            LOADS(bE0, bE1, bX, j + 7);
            CONSUME(cE0, cE1, cX);
            LOADS(cE0, cE1, cX, j + 8);
            CONSUME(dE0, dE1, dX);
            LOADS(dE0, dE1, dX, j + 9);
            CONSUME(eE0, eE1, eX);
            LOADS(eE0, eE1, eX, j + 10);
            CONSUME(fE0, fE1, fX);
            j += 6;
        }
        if (j < cnt)     CONSUME(aE0, aE1, aX);
        if (j + 1 < cnt) CONSUME(bE0, bE1, bX);
        if (j + 2 < cnt) CONSUME(cE0, cE1, cX);
        if (j + 3 < cnt) CONSUME(dE0, dE1, dX);
        if (j + 4 < cnt) CONSUME(eE0, eE1, eX);
#undef LOADS
#undef CONSUME
    }
    float rden = (den > 0.f) ? (1.f / den) : 0.f;
    float2 gb = *(const float2*)(gat_bias + c);
    float ox = n0 * rden + gb.x, oy = n1 * rden + gb.y;
    gatp[node * 64 + lane] = pkbf(ox, oy);
}

// ---------------------------------------------------------------------------
// K6 (MFMA): residual GEMM+LN (ident, using nf already in LDS) + MLP + LN +
// residual add. gat read pre-packed bf16.
// ---------------------------------------------------------------------------
__global__ __launch_bounds__(256, 3) void k6_mlp_mfma(
    const float* __restrict__ nf, const unsigned* __restrict__ gatp,
    const unsigned short* __restrict__ Wtres, const float* __restrict__ res_b,
    const float* __restrict__ res_g, const float* __restrict__ res_be,
    const unsigned short* __restrict__ Wt0, const float* __restrict__ b0,
    const float* __restrict__ g0, const float* __restrict__ be0,
    const unsigned short* __restrict__ Wt1, const float* __restrict__ b1,
    const float* __restrict__ g1, const float* __restrict__ be1,
    float* __restrict__ out)
{
    __shared__ __align__(16) unsigned LDS[64 * 100];
    const int tid = threadIdx.x;
    const int node0 = blockIdx.x * 64;

    for (int i = tid; i < 64 * 96; i += 256) {
        int n = i / 96, c2 = i - n * 96;
        int gn = node0 + n;
        unsigned pv = 0u;
        if (gn < NN) {
            if (c2 < 32) {
                float2 v = *(const float2*)(nf + gn * 64 + 2 * c2);
                pv = pkbf(v.x, v.y);
            } else {
                pv = gatp[gn * 64 + (c2 - 32)];
            }
        }
        LDS[n * 100 + c2] = pv;
    }
    __syncthreads();

    const int lane = tid & 63, w = tid >> 6;
    const int c = lane & 15, ko = lane >> 4;
    const int lrow = w * 16 + 4 * ko;

    // ---- residual GEMM (nf @ res_W), A = first 64 cols of LDS ----
    f32x4 accr[8];
    #pragma unroll
    for (int nt = 0; nt < 8; ++nt) accr[nt] = f32x4{0.f, 0.f, 0.f, 0.f};
    #pragma unroll
    for (int kb = 0; kb < 2; ++kb) {
        bf16x8 a = *(const bf16x8*)((const unsigned short*)LDS +
                                    (w * 16 + c) * 200 + kb * 32 + ko * 8);
        #pragma unroll
        for (int nt = 0; nt < 8; ++nt) {
            bf16x8 b = *(const bf16x8*)(Wtres + (nt * 16 + c) * 64 + kb * 32 + ko * 8);
            accr[nt] = __builtin_amdgcn_mfma_f32_16x16x32_bf16(a, b, accr[nt], 0, 0, 0);
        }
    }

    // ---- layer-0 GEMM ([nf|gat] @ W0) ----
    f32x4 acc[8];
    #pragma unroll
    for (int nt = 0; nt < 8; ++nt) acc[nt] = f32x4{0.f, 0.f, 0.f, 0.f};
    #pragma unroll
    for (int kb = 0; kb < 6; ++kb) {
        bf16x8 a = *(const bf16x8*)((const unsigned short*)LDS +
                                    (w * 16 + c) * 200 + kb * 32 + ko * 8);
        #pragma unroll
        for (int nt = 0; nt < 8; ++nt) {
            bf16x8 b = *(const bf16x8*)(Wt0 + (nt * 16 + c) * 192 + kb * 32 + ko * 8);
            acc[nt] = __builtin_amdgcn_mfma_f32_16x16x32_bf16(a, b, acc[nt], 0, 0, 0);
        }
    }

    float bv[8], gv[8], tv[8];
    #pragma unroll
    for (int nt = 0; nt < 8; ++nt) {
        bv[nt] = b0[nt * 16 + c];
        gv[nt] = g0[nt * 16 + c];
        tv[nt] = be0[nt * 16 + c];
    }
    __syncthreads();

    unsigned short* Hs = (unsigned short*)LDS;
    #pragma unroll
    for (int reg = 0; reg < 4; ++reg) {
        float sum = 0.f, sq = 0.f, hv[8];
        #pragma unroll
        for (int nt = 0; nt < 8; ++nt) {
            float v = acc[nt][reg] + bv[nt];
            hv[nt] = v; sum += v; sq += v * v;
        }
        #pragma unroll
        for (int m = 1; m <= 8; m <<= 1) {
            sum += __shfl_xor(sum, m, 64);
            sq  += __shfl_xor(sq, m, 64);
        }
        float mean = sum * (1.f / 128.f);
        float inv  = rsqrtf(sq * (1.f / 128.f) - mean * mean + 1e-5f);
        #pragma unroll
        for (int nt = 0; nt < 8; ++nt) {
            float h = fmaxf((hv[nt] - mean) * inv * gv[nt] + tv[nt], 0.f);
            Hs[(lrow + reg) * 136 + nt * 16 + c] = bfb(h);
        }
    }
    __syncthreads();

    // ---- layer-1 GEMM ----
    #pragma unroll
    for (int nt = 0; nt < 8; ++nt) acc[nt] = f32x4{0.f, 0.f, 0.f, 0.f};
    #pragma unroll
    for (int kb = 0; kb < 4; ++kb) {
        bf16x8 a = *(const bf16x8*)((const unsigned short*)LDS +
                                    (w * 16 + c) * 136 + kb * 32 + ko * 8);
        #pragma unroll
        for (int nt = 0; nt < 8; ++nt) {
            bf16x8 b = *(const bf16x8*)(Wt1 + (nt * 16 + c) * 128 + kb * 32 + ko * 8);
            acc[nt] = __builtin_amdgcn_mfma_f32_16x16x32_bf16(a, b, acc[nt], 0, 0, 0);
        }
    }

    float bvr[8], gvr[8], tvr[8];
    #pragma unroll
    for (int nt = 0; nt < 8; ++nt) {
        bv[nt]  = b1[nt * 16 + c];
        gv[nt]  = g1[nt * 16 + c];
        tv[nt]  = be1[nt * 16 + c];
        bvr[nt] = res_b[nt * 16 + c];
        gvr[nt] = res_g[nt * 16 + c];
        tvr[nt] = res_be[nt * 16 + c];
    }
    #pragma unroll
    for (int reg = 0; reg < 4; ++reg) {
        float sum = 0.f, sq = 0.f, hv[8];
        float sumr = 0.f, sqr = 0.f, rv[8];
        #pragma unroll
        for (int nt = 0; nt < 8; ++nt) {
            float v = acc[nt][reg] + bv[nt];
            hv[nt] = v; sum += v; sq += v * v;
            float u = accr[nt][reg] + bvr[nt];
            rv[nt] = u; sumr += u; sqr += u * u;
        }
        #pragma unroll
        for (int m = 1; m <= 8; m <<= 1) {
            sum  += __shfl_xor(sum, m, 64);
            sq   += __shfl_xor(sq, m, 64);
            sumr += __shfl_xor(sumr, m, 64);
            sqr  += __shfl_xor(sqr, m, 64);
        }
        float mean  = sum  * (1.f / 128.f);
        float inv   = rsqrtf(sq  * (1.f / 128.f) - mean  * mean  + 1e-5f);
        float meanr = sumr * (1.f / 128.f);
        float invr  = rsqrtf(sqr * (1.f / 128.f) - meanr * meanr + 1e-5f);
        int row = node0 + lrow + reg;
        if (row < NN) {
            #pragma unroll
            for (int nt = 0; nt < 8; ++nt) {
                float h  = fmaxf((hv[nt] - mean) * inv * gv[nt] + tv[nt], 0.f);
                float id = (rv[nt] - meanr) * invr * gvr[nt] + tvr[nt];
                int col = nt * 16 + c;
                out[row * 128 + col] = id + h;
            }
        }
    }
}

// ---------------------------------------------------------------------------
extern "C" void kernel_launch(void* const* d_in, const int* in_sizes, int n_in,
                              void* d_out, int out_size, void* d_ws, size_t ws_size,
                              hipStream_t stream)
{
    const float* nf       = (const float*)d_in[0];
    const float* ef       = (const float*)d_in[1];
    const int*   eidx     = (const int*)d_in[2];
    const float* W_l      = (const float*)d_in[3];
    const float* b_l      = (const float*)d_in[4];
    const float* W_r      = (const float*)d_in[5];
    const float* b_r      = (const float*)d_in[6];
    const float* W_e      = (const float*)d_in[7];
    const float* att      = (const float*)d_in[8];
    const float* gat_bias = (const float*)d_in[9];
    const float* res_W    = (const float*)d_in[10];
    const float* res_b    = (const float*)d_in[11];
    const float* res_g    = (const float*)d_in[12];
    const float* res_beta = (const float*)d_in[13];
    const float* W0       = (const float*)d_in[14];
    const float* b0       = (const float*)d_in[15];
    const float* g0       = (const float*)d_in[16];
    const float* beta0    = (const float*)d_in[17];
    const float* W1       = (const float*)d_in[18];
    const float* b1       = (const float*)d_in[19];
    const float* g1       = (const float*)d_in[20];
    const float* beta1    = (const float*)d_in[21];
    float* out = (float*)d_out;

    char* ws = (char*)d_ws;
    size_t off = 0;
    auto alloc = [&](size_t bytes) -> void* {
        void* p = ws + off;
        off += (bytes + 255) & ~(size_t)255;
        return p;
    };
    unsigned* xlp  = (unsigned*)alloc((size_t)NN * 64 * 4);   // x_l packed f16x2
    unsigned* xrp  = (unsigned*)alloc((size_t)NN * 64 * 4);   // x_r packed f16x2
    int* deg       = (int*)alloc((size_t)NN * 4);
    int* row_start = (int*)alloc((size_t)(NN + 1) * 4);
    int* rank      = (int*)alloc((size_t)NE * 4);
    int* bsum      = (int*)alloc((size_t)(NB + 1) * 4);
    int2* csr_es   = (int2*)alloc((size_t)NE * 8);
    unsigned* gatp = (unsigned*)alloc((size_t)NN * 64 * 4);   // gat packed bf16x2
    unsigned short* Wtl   = (unsigned short*)alloc(8192 * 2);
    unsigned short* Wtr   = (unsigned short*)alloc(8192 * 2);
    unsigned short* Wtres = (unsigned short*)alloc(8192 * 2);
    unsigned short* Wt0   = (unsigned short*)alloc(24576 * 2);
    unsigned short* Wt1   = (unsigned short*)alloc(16384 * 2);
    unsigned* Wep = (unsigned*)alloc(1024 * 4);
    unsigned* efp = (unsigned*)alloc((size_t)NE * 8 * 4);

    k0_prep<<<NB, 256, 0, stream>>>(W_l, W_r, res_W, W0, W1, W_e,
                                    Wtl, Wtr, Wtres, Wt0, Wt1, Wep,
                                    deg, row_start);

    ka_nodes_degree<<<K1B + (NE + 255) / 256, 256, 0, stream>>>(
        nf, Wtl, b_l, Wtr, b_r,
        xlp, xrp, eidx, deg, rank, ef, efp);

    k3a_blocksum<<<NB, 256, 0, stream>>>(deg, bsum);
    k3c_apply<<<NB, 256, 0, stream>>>(deg, bsum, row_start);

    k4_scatter<<<(NE + 255) / 256, 256, 0, stream>>>(eidx, row_start, rank, csr_es);

    k5_attn_aggregate<<<(NN * 64 + 255) / 256, 256, 0, stream>>>(
        csr_es, row_start, efp, Wep, att, xlp, xrp, gat_bias, gatp);

    k6_mlp_mfma<<<(NN + 63) / 64, 256, 0, stream>>>(
        nf, gatp, Wtres, res_b, res_g, res_beta,
        Wt0, b0, g0, beta0, Wt1, b1, g1, beta1, out);
}

// Round 7
// 330.619 us; speedup vs baseline: 1.0283x; 1.0283x over previous
//
#include <hip/hip_runtime.h>

#define NN 50000
#define NE 800000
#define NB 196   // (NN+255)/256
#define K1B 782  // (NN+63)/64

typedef __attribute__((ext_vector_type(8))) short bf16x8;
typedef __attribute__((ext_vector_type(4))) float f32x4;
typedef __attribute__((ext_vector_type(2))) _Float16 h2f;

__device__ __forceinline__ int rfl(int v) { return __builtin_amdgcn_readfirstlane(v); }

__device__ __forceinline__ unsigned short bfb(float x) {
    union { float f; unsigned u; } v; v.f = x;
    unsigned r = v.u + 0x7FFFu + ((v.u >> 16) & 1u);
    return (unsigned short)(r >> 16);
}
__device__ __forceinline__ unsigned pkbf(float lo, float hi) {
    return ((unsigned)bfb(hi) << 16) | (unsigned)bfb(lo);
}
__device__ __forceinline__ unsigned pkh2(float a, float b) {
    union { h2f h; unsigned u; } x;
    x.h.x = (_Float16)a; x.h.y = (_Float16)b;
    return x.u;
}
__device__ __forceinline__ float fdot2u(unsigned a, unsigned b, float c) {
    union { unsigned u; h2f h; } ua, ub; ua.u = a; ub.u = b;
    return __builtin_amdgcn_fdot2(ua.h, ub.h, c, false);
}

// 16-lane sum, xor DPP pattern (round-2 summation order, absmax 0.03125).
__device__ __forceinline__ float dpp_reduce16(float p) {
    int t;
    t = __builtin_amdgcn_update_dpp(0, __float_as_int(p), 0xB1, 0xF, 0xF, false);
    p += __int_as_float(t);
    t = __builtin_amdgcn_update_dpp(0, __float_as_int(p), 0x4E, 0xF, 0xF, false);
    p += __int_as_float(t);
    t = __builtin_amdgcn_update_dpp(0, __float_as_int(p), 0x124, 0xF, 0xF, false);
    p += __int_as_float(t);
    t = __builtin_amdgcn_update_dpp(0, __float_as_int(p), 0x128, 0xF, 0xF, false);
    p += __int_as_float(t);
    return p;
}

// 2^x via single v_exp_f32 (input pre-scaled by log2(e) upstream).
__device__ __forceinline__ float exp2_hw(float x) {
    float r;
    asm("v_exp_f32 %0, %1" : "=v"(r) : "v"(x));
    return r;
}

// ---------------------------------------------------------------------------
// K0 (tiny prep): bf16-transpose all weights, f16-pair W_e, zero deg, and
// statically set row_start[NN]=NE.
// ---------------------------------------------------------------------------
__global__ __launch_bounds__(256) void k0_prep(
    const float* __restrict__ W_l, const float* __restrict__ W_r,
    const float* __restrict__ res_W, const float* __restrict__ W0,
    const float* __restrict__ W1, const float* __restrict__ W_e,
    unsigned short* __restrict__ Wtl, unsigned short* __restrict__ Wtr,
    unsigned short* __restrict__ Wtres, unsigned short* __restrict__ Wt0,
    unsigned short* __restrict__ Wt1,
    unsigned* __restrict__ Wep,
    int* __restrict__ deg, int* __restrict__ row_start)
{
    const int t0 = blockIdx.x * 256 + threadIdx.x;
    if (t0 < 24576) { int n = t0 / 192, k = t0 - n * 192; Wt0[t0] = bfb(W0[k * 128 + n]); }
    if (t0 < 16384) { int n = t0 >> 7, k = t0 & 127; Wt1[t0] = bfb(W1[k * 128 + n]); }
    if (t0 < 8192) {
        int n = t0 >> 6, k = t0 & 63;
        Wtl[t0]   = bfb(W_l[k * 128 + n]);
        Wtr[t0]   = bfb(W_r[k * 128 + n]);
        Wtres[t0] = bfb(res_W[k * 128 + n]);
    }
    if (t0 < 1024) {  // Wep[c][j] = (W_e[2j][c], W_e[2j+1][c])
        int c = t0 >> 3, j = t0 & 7;
        Wep[t0] = pkh2(W_e[(2 * j) * 128 + c], W_e[(2 * j + 1) * 128 + c]);
    }
    if (t0 < NN) deg[t0] = 0;
    if (t0 == 0) row_start[NN] = NE;
}

// ---------------------------------------------------------------------------
// KA (fused): blocks [0,K1B) do the MFMA node transforms (x_l, x_r -> packed
// f16; ident f32); blocks [K1B, ...) do degree count + per-edge rank AND pack
// this edge's features f32->f16 (overlaps under the random-atomic latency).
// ---------------------------------------------------------------------------
__global__ __launch_bounds__(256, 4) void ka_nodes_degree(
    const float* __restrict__ nf,
    const unsigned short* __restrict__ Wtl, const float* __restrict__ b_l,
    const unsigned short* __restrict__ Wtr, const float* __restrict__ b_r,
    const unsigned short* __restrict__ Wtres, const float* __restrict__ res_b,
    const float* __restrict__ res_g, const float* __restrict__ res_beta,
    unsigned* __restrict__ xlp, unsigned* __restrict__ xrp,
    float* __restrict__ ident,
    const int* __restrict__ eidx, int* __restrict__ deg, int* __restrict__ rank,
    const float* __restrict__ ef, unsigned* __restrict__ efp)
{
    if (blockIdx.x >= K1B) {
        int e = (blockIdx.x - K1B) * 256 + threadIdx.x;
        if (e < NE) {
            rank[e] = atomicAdd(deg + eidx[NE + e], 1);
            const float4* er = (const float4*)(ef + (size_t)e * 16);
            float4 v0 = er[0], v1 = er[1], v2 = er[2], v3 = er[3];
            uint4 o0, o1;
            o0.x = pkh2(v0.x, v0.y); o0.y = pkh2(v0.z, v0.w);
            o0.z = pkh2(v1.x, v1.y); o0.w = pkh2(v1.z, v1.w);
            o1.x = pkh2(v2.x, v2.y); o1.y = pkh2(v2.z, v2.w);
            o1.z = pkh2(v3.x, v3.y); o1.w = pkh2(v3.z, v3.w);
            *(uint4*)(efp + (size_t)e * 8)     = o0;
            *(uint4*)(efp + (size_t)e * 8 + 4) = o1;
        }
        return;
    }
    __shared__ __align__(16) unsigned As32[64 * 36];
    const int tid = threadIdx.x;
    const int node0 = blockIdx.x * 64;

    for (int i = tid; i < 64 * 32; i += 256) {
        int n = i >> 5, c2 = i & 31;
        int gn = node0 + n;
        float2 v = make_float2(0.f, 0.f);
        if (gn < NN) v = *(const float2*)(nf + gn * 64 + 2 * c2);
        As32[n * 36 + c2] = pkbf(v.x, v.y);
    }
    __syncthreads();

    const int lane = tid & 63, w = tid >> 6;
    const int c = lane & 15, ko = lane >> 4;
    const unsigned short* As = (const unsigned short*)As32;
    bf16x8 a0 = *(const bf16x8*)(As + (w * 16 + c) * 72 + 0 * 32 + ko * 8);
    bf16x8 a1 = *(const bf16x8*)(As + (w * 16 + c) * 72 + 1 * 32 + ko * 8);
    const int lrow0 = node0 + w * 16 + 4 * ko;

    #pragma unroll
    for (int p = 0; p < 3; ++p) {
        const unsigned short* Wt = (p == 0) ? Wtl : (p == 1) ? Wtr : Wtres;
        f32x4 acc[8];
        #pragma unroll
        for (int nt = 0; nt < 8; ++nt) acc[nt] = f32x4{0.f, 0.f, 0.f, 0.f};
        #pragma unroll
        for (int nt = 0; nt < 8; ++nt) {
            bf16x8 bf0 = *(const bf16x8*)(Wt + (nt * 16 + c) * 64 + 0 * 32 + ko * 8);
            acc[nt] = __builtin_amdgcn_mfma_f32_16x16x32_bf16(a0, bf0, acc[nt], 0, 0, 0);
            bf16x8 bf1 = *(const bf16x8*)(Wt + (nt * 16 + c) * 64 + 1 * 32 + ko * 8);
            acc[nt] = __builtin_amdgcn_mfma_f32_16x16x32_bf16(a1, bf1, acc[nt], 0, 0, 0);
        }
        if (p < 2) {
            // pack channel pairs (2k, 2k+1) to f16x2; partner lives in lane^1.
            const float* bias = (p == 0) ? b_l : b_r;
            unsigned* outp = (p == 0) ? xlp : xrp;
            float bv[8];
            #pragma unroll
            for (int nt = 0; nt < 8; ++nt) bv[nt] = bias[nt * 16 + c];
            #pragma unroll
            for (int reg = 0; reg < 4; ++reg) {
                int row = lrow0 + reg;
                #pragma unroll
                for (int nt = 0; nt < 8; ++nt) {
                    float v = acc[nt][reg] + bv[nt];
                    float v2 = __shfl_xor(v, 1, 64);
                    if (row < NN && (lane & 1) == 0)
                        outp[row * 64 + nt * 8 + (c >> 1)] = pkh2(v, v2);
                }
            }
        } else {
            float bv[8], gv[8], tv[8];
            #pragma unroll
            for (int nt = 0; nt < 8; ++nt) {
                bv[nt] = res_b[nt * 16 + c];
                gv[nt] = res_g[nt * 16 + c];
                tv[nt] = res_beta[nt * 16 + c];
            }
            #pragma unroll
            for (int reg = 0; reg < 4; ++reg) {
                float sum = 0.f, sq = 0.f, hv[8];
                #pragma unroll
                for (int nt = 0; nt < 8; ++nt) {
                    float v = acc[nt][reg] + bv[nt];
                    hv[nt] = v; sum += v; sq += v * v;
                }
                #pragma unroll
                for (int m = 1; m <= 8; m <<= 1) {
                    sum += __shfl_xor(sum, m, 64);
                    sq  += __shfl_xor(sq, m, 64);
                }
                float mean = sum * (1.f / 128.f);
                float inv  = rsqrtf(sq * (1.f / 128.f) - mean * mean + 1e-5f);
                int row = lrow0 + reg;
                if (row < NN) {
                    #pragma unroll
                    for (int nt = 0; nt < 8; ++nt)
                        ident[row * 128 + nt * 16 + c] =
                            (hv[nt] - mean) * inv * gv[nt] + tv[nt];
                }
            }
        }
    }
}

// ---------------------------------------------------------------------------
// K3a: per-block degree sums.
// ---------------------------------------------------------------------------
__global__ __launch_bounds__(256) void k3a_blocksum(
    const int* __restrict__ deg, int* __restrict__ bsum)
{
    __shared__ int ws[4];
    int i = blockIdx.x * 256 + threadIdx.x;
    int v = (i < NN) ? deg[i] : 0;
    #pragma unroll
    for (int m = 32; m >= 1; m >>= 1) v += __shfl_xor(v, m, 64);
    if ((threadIdx.x & 63) == 0) ws[threadIdx.x >> 6] = v;
    __syncthreads();
    if (threadIdx.x == 0) bsum[blockIdx.x] = ws[0] + ws[1] + ws[2] + ws[3];
}

// ---------------------------------------------------------------------------
// K3c: block-local scan + prefix of bsum -> row_start.
// ---------------------------------------------------------------------------
__global__ __launch_bounds__(256) void k3c_apply(
    const int* __restrict__ deg, const int* __restrict__ bsum,
    int* __restrict__ row_start)
{
    __shared__ int wsum[4];
    __shared__ int roff[4];
    const int tid = threadIdx.x, lane = tid & 63, wid = tid >> 6;
    int bv = (tid < blockIdx.x) ? bsum[tid] : 0;   // blockIdx.x <= 195 < 256
    #pragma unroll
    for (int m = 32; m >= 1; m >>= 1) bv += __shfl_xor(bv, m, 64);
    if (lane == 0) roff[wid] = bv;

    int i = blockIdx.x * 256 + tid;
    int v = (i < NN) ? deg[i] : 0;
    int sc = v;
    #pragma unroll
    for (int m = 1; m < 64; m <<= 1) {
        int t = __shfl_up(sc, m, 64);
        if (lane >= m) sc += t;
    }
    if (lane == 63) wsum[wid] = sc;
    __syncthreads();
    int off = roff[0] + roff[1] + roff[2] + roff[3];
    for (int w = 0; w < wid; ++w) off += wsum[w];
    int excl = off + sc - v;
    if (i < NN) row_start[i] = excl;
}

// ---------------------------------------------------------------------------
// K4: pure scatter (no atomics): pos = row_start[dst] + rank[e].
// ---------------------------------------------------------------------------
__global__ __launch_bounds__(256) void k4_scatter(
    const int* __restrict__ eidx, const int* __restrict__ row_start,
    const int* __restrict__ rank, int2* __restrict__ csr_es)
{
    int e = blockIdx.x * 256 + threadIdx.x;
    if (e >= NE) return;
    int dst = eidx[NE + e];
    csr_es[row_start[dst] + rank[e]] = make_int2(e, eidx[e]);
}

// ---------------------------------------------------------------------------
// K5: fused GATv2 attention + aggregation. One wave per node.
// Chunked CSR preload + readlane (SGPR eid/src, scalar-side ef loads).
// Depth-6 rotating pipeline. exp via v_exp_f32 (att pre-scaled by log2 e).
// x_r read as packed f16; gat_out written as packed bf16 (identical to the
// conversion k6 was doing anyway).
// ---------------------------------------------------------------------------
__global__ __launch_bounds__(256, 4) void k5_attn_aggregate(
    const int2* __restrict__ csr_es, const int* __restrict__ row_start,
    const unsigned* __restrict__ efp, const unsigned* __restrict__ Wep,
    const float* __restrict__ att,
    const unsigned* __restrict__ xlp, const unsigned* __restrict__ xrp,
    const float* __restrict__ gat_bias,
    unsigned* __restrict__ gatp)
{
    const int lane = threadIdx.x & 63;
    const int node = (blockIdx.x * 256 + threadIdx.x) >> 6;
    if (node >= NN) return;
    const int c = lane * 2;

    uint4 t0 = *(const uint4*)(Wep + c * 8);
    uint4 t1 = *(const uint4*)(Wep + c * 8 + 4);
    uint4 t2 = *(const uint4*)(Wep + (c + 1) * 8);
    uint4 t3 = *(const uint4*)(Wep + (c + 1) * 8 + 4);
    unsigned wx0 = t0.x, wx1 = t0.y, wx2 = t0.z, wx3 = t0.w;
    unsigned wx4 = t1.x, wx5 = t1.y, wx6 = t1.z, wx7 = t1.w;
    unsigned wy0 = t2.x, wy1 = t2.y, wy2 = t2.z, wy3 = t2.w;
    unsigned wy4 = t3.x, wy5 = t3.y, wy6 = t3.z, wy7 = t3.w;

    const float LOG2E = 1.44269504088896340736f;
    float2 a2 = *(const float2*)(att + c);
    a2.x *= LOG2E; a2.y *= LOG2E;
    float2 xr;
    {
        union { unsigned u; h2f h; } uxr;
        uxr.u = xrp[node * 64 + lane];
        xr.x = (float)uxr.h.x; xr.y = (float)uxr.h.y;
    }
    const uint4* __restrict__ efq = (const uint4*)efp;
    const unsigned* __restrict__ xlc = xlp + lane;

    const int sj  = rfl(row_start[node]);
    const int epj = rfl(row_start[node + 1]);

    float den = 0.f, n0 = 0.f, n1 = 0.f;

    for (int base = sj; base < epj; base += 64) {
        const int cnt = min(64, epj - base);
        int pidx = base + lane; if (pidx > NE - 1) pidx = NE - 1;
        const int2 mc = csr_es[pidx];   // coalesced: this chunk's (eid, src)

        uint4 aE0, aE1, bE0, bE1, cE0, cE1, dE0, dE1, eE0, eE1, fE0, fE1;
        unsigned aX, bX, cX, dX, eX, fX;

#define LOADS(E0_, E1_, X_, K_)                                            \
        { int kk = (K_); if (kk >= cnt) kk = cnt - 1;                      \
          int eid  = __builtin_amdgcn_readlane(mc.x, kk);                  \
          int srcn = __builtin_amdgcn_readlane(mc.y, kk);                  \
          E0_ = efq[eid * 2 + 0]; E1_ = efq[eid * 2 + 1];                  \
          X_  = xlc[srcn * 64]; }

#define CONSUME(E0_, E1_, X_)                                              \
        { asm volatile("" : "+v"(wx0), "+v"(wx1), "+v"(wx2), "+v"(wx3),    \
                            "+v"(wx4), "+v"(wx5), "+v"(wx6), "+v"(wx7));   \
          asm volatile("" : "+v"(wy0), "+v"(wy1), "+v"(wy2), "+v"(wy3),    \
                            "+v"(wy4), "+v"(wy5), "+v"(wy6), "+v"(wy7));   \
          union { unsigned u; h2f h; } ux; ux.u = (X_);                    \
          float cx0 = (float)ux.h.x, cx1 = (float)ux.h.y;                  \
          float ax = cx0 + xr.x;                                           \
          float ay = cx1 + xr.y;                                           \
          float bx = 0.f, by = 0.f;                                        \
          ax = fdot2u((E0_).x, wx0, ax);  ay = fdot2u((E0_).x, wy0, ay);   \
          bx = fdot2u((E0_).y, wx1, bx);  by = fdot2u((E0_).y, wy1, by);   \
          ax = fdot2u((E0_).z, wx2, ax);  ay = fdot2u((E0_).z, wy2, ay);   \
          bx = fdot2u((E0_).w, wx3, bx);  by = fdot2u((E0_).w, wy3, by);   \
          ax = fdot2u((E1_).x, wx4, ax);  ay = fdot2u((E1_).x, wy4, ay);   \
          bx = fdot2u((E1_).y, wx5, bx);  by = fdot2u((E1_).y, wy5, by);   \
          ax = fdot2u((E1_).z, wx6, ax);  ay = fdot2u((E1_).z, wy6, ay);   \
          bx = fdot2u((E1_).w, wx7, bx);  by = fdot2u((E1_).w, wy7, by);   \
          float evx = ax + bx;                                             \
          float evy = ay + by;                                             \
          float lx = fmaxf(evx, 0.2f * evx);                               \
          float ly = fmaxf(evy, 0.2f * evy);                               \
          float p = lx * a2.x + ly * a2.y;                                 \
          p = dpp_reduce16(p);                                             \
          float ev = exp2_hw(p);                                           \
          den += ev; n0 += ev * cx0; n1 += ev * cx1; }

        LOADS(aE0, aE1, aX, 0);
        LOADS(bE0, bE1, bX, 1);
        LOADS(cE0, cE1, cX, 2);
        LOADS(dE0, dE1, dX, 3);
        LOADS(eE0, eE1, eX, 4);
        int j = 0;
        while (j + 6 <= cnt) {
            LOADS(fE0, fE1, fX, j + 5);
            CONSUME(aE0, aE1, aX);
            LOADS(aE0, aE1, aX, j + 6);
            CONSUME(bE0, bE1, bX);
            LOADS(bE0, bE1, bX, j + 7);
            CONSUME(cE0, cE1, cX);
            LOADS(cE0, cE1, cX, j + 8);
            CONSUME(dE0, dE1, dX);
            LOADS(dE0, dE1, dX, j + 9);
            CONSUME(eE0, eE1, eX);
            LOADS(eE0, eE1, eX, j + 10);
            CONSUME(fE0, fE1, fX);
            j += 6;
        }
        if (j < cnt)     CONSUME(aE0, aE1, aX);
        if (j + 1 < cnt) CONSUME(bE0, bE1, bX);
        if (j + 2 < cnt) CONSUME(cE0, cE1, cX);
        if (j + 3 < cnt) CONSUME(dE0, dE1, dX);
        if (j + 4 < cnt) CONSUME(eE0, eE1, eX);
#undef LOADS
#undef CONSUME
    }
    float rden = (den > 0.f) ? (1.f / den) : 0.f;
    float2 gb = *(const float2*)(gat_bias + c);
    float ox = n0 * rden + gb.x, oy = n1 * rden + gb.y;
    gatp[node * 64 + lane] = pkbf(ox, oy);
}

// ---------------------------------------------------------------------------
// K6 (MFMA): MLP + LN + residual add. gat read pre-packed bf16; ident f32.
// ---------------------------------------------------------------------------
__global__ __launch_bounds__(256, 4) void k6_mlp_mfma(
    const float* __restrict__ nf, const unsigned* __restrict__ gatp,
    const float* __restrict__ ident,
    const unsigned short* __restrict__ Wt0, const float* __restrict__ b0,
    const float* __restrict__ g0, const float* __restrict__ be0,
    const unsigned short* __restrict__ Wt1, const float* __restrict__ b1,
    const float* __restrict__ g1, const float* __restrict__ be1,
    float* __restrict__ out)
{
    __shared__ __align__(16) unsigned LDS[64 * 100];
    const int tid = threadIdx.x;
    const int node0 = blockIdx.x * 64;

    for (int i = tid; i < 64 * 96; i += 256) {
        int n = i / 96, c2 = i - n * 96;
        int gn = node0 + n;
        unsigned pv = 0u;
        if (gn < NN) {
            if (c2 < 32) {
                float2 v = *(const float2*)(nf + gn * 64 + 2 * c2);
                pv = pkbf(v.x, v.y);
            } else {
                pv = gatp[gn * 64 + (c2 - 32)];
            }
        }
        LDS[n * 100 + c2] = pv;
    }
    __syncthreads();

    const int lane = tid & 63, w = tid >> 6;
    const int c = lane & 15, ko = lane >> 4;
    const int lrow = w * 16 + 4 * ko;

    f32x4 acc[8];
    #pragma unroll
    for (int nt = 0; nt < 8; ++nt) acc[nt] = f32x4{0.f, 0.f, 0.f, 0.f};

    #pragma unroll
    for (int kb = 0; kb < 6; ++kb) {
        bf16x8 a = *(const bf16x8*)((const unsigned short*)LDS +
                                    (w * 16 + c) * 200 + kb * 32 + ko * 8);
        #pragma unroll
        for (int nt = 0; nt < 8; ++nt) {
            bf16x8 b = *(const bf16x8*)(Wt0 + (nt * 16 + c) * 192 + kb * 32 + ko * 8);
            acc[nt] = __builtin_amdgcn_mfma_f32_16x16x32_bf16(a, b, acc[nt], 0, 0, 0);
        }
    }

    float bv[8], gv[8], tv[8];
    #pragma unroll
    for (int nt = 0; nt < 8; ++nt) {
        bv[nt] = b0[nt * 16 + c];
        gv[nt] = g0[nt * 16 + c];
        tv[nt] = be0[nt * 16 + c];
    }
    __syncthreads();

    unsigned short* Hs = (unsigned short*)LDS;
    #pragma unroll
    for (int reg = 0; reg < 4; ++reg) {
        float sum = 0.f, sq = 0.f, hv[8];
        #pragma unroll
        for (int nt = 0; nt < 8; ++nt) {
            float v = acc[nt][reg] + bv[nt];
            hv[nt] = v; sum += v; sq += v * v;
        }
        #pragma unroll
        for (int m = 1; m <= 8; m <<= 1) {
            sum += __shfl_xor(sum, m, 64);
            sq  += __shfl_xor(sq, m, 64);
        }
        float mean = sum * (1.f / 128.f);
        float inv  = rsqrtf(sq * (1.f / 128.f) - mean * mean + 1e-5f);
        #pragma unroll
        for (int nt = 0; nt < 8; ++nt) {
            float h = fmaxf((hv[nt] - mean) * inv * gv[nt] + tv[nt], 0.f);
            Hs[(lrow + reg) * 136 + nt * 16 + c] = bfb(h);
        }
    }
    __syncthreads();

    #pragma unroll
    for (int nt = 0; nt < 8; ++nt) acc[nt] = f32x4{0.f, 0.f, 0.f, 0.f};
    #pragma unroll
    for (int kb = 0; kb < 4; ++kb) {
        bf16x8 a = *(const bf16x8*)((const unsigned short*)LDS +
                                    (w * 16 + c) * 136 + kb * 32 + ko * 8);
        #pragma unroll
        for (int nt = 0; nt < 8; ++nt) {
            bf16x8 b = *(const bf16x8*)(Wt1 + (nt * 16 + c) * 128 + kb * 32 + ko * 8);
            acc[nt] = __builtin_amdgcn_mfma_f32_16x16x32_bf16(a, b, acc[nt], 0, 0, 0);
        }
    }

    #pragma unroll
    for (int nt = 0; nt < 8; ++nt) {
        bv[nt] = b1[nt * 16 + c];
        gv[nt] = g1[nt * 16 + c];
        tv[nt] = be1[nt * 16 + c];
    }
    #pragma unroll
    for (int reg = 0; reg < 4; ++reg) {
        float sum = 0.f, sq = 0.f, hv[8];
        #pragma unroll
        for (int nt = 0; nt < 8; ++nt) {
            float v = acc[nt][reg] + bv[nt];
            hv[nt] = v; sum += v; sq += v * v;
        }
        #pragma unroll
        for (int m = 1; m <= 8; m <<= 1) {
            sum += __shfl_xor(sum, m, 64);
            sq  += __shfl_xor(sq, m, 64);
        }
        float mean = sum * (1.f / 128.f);
        float inv  = rsqrtf(sq * (1.f / 128.f) - mean * mean + 1e-5f);
        int row = node0 + lrow + reg;
        if (row < NN) {
            #pragma unroll
            for (int nt = 0; nt < 8; ++nt) {
                float h = fmaxf((hv[nt] - mean) * inv * gv[nt] + tv[nt], 0.f);
                int col = nt * 16 + c;
                out[row * 128 + col] = ident[row * 128 + col] + h;
            }
        }
    }
}

// ---------------------------------------------------------------------------
extern "C" void kernel_launch(void* const* d_in, const int* in_sizes, int n_in,
                              void* d_out, int out_size, void* d_ws, size_t ws_size,
                              hipStream_t stream)
{
    const float* nf       = (const float*)d_in[0];
    const float* ef       = (const float*)d_in[1];
    const int*   eidx     = (const int*)d_in[2];
    const float* W_l      = (const float*)d_in[3];
    const float* b_l      = (const float*)d_in[4];
    const float* W_r      = (const float*)d_in[5];
    const float* b_r      = (const float*)d_in[6];
    const float* W_e      = (const float*)d_in[7];
    const float* att      = (const float*)d_in[8];
    const float* gat_bias = (const float*)d_in[9];
    const float* res_W    = (const float*)d_in[10];
    const float* res_b    = (const float*)d_in[11];
    const float* res_g    = (const float*)d_in[12];
    const float* res_beta = (const float*)d_in[13];
    const float* W0       = (const float*)d_in[14];
    const float* b0       = (const float*)d_in[15];
    const float* g0       = (const float*)d_in[16];
    const float* beta0    = (const float*)d_in[17];
    const float* W1       = (const float*)d_in[18];
    const float* b1       = (const float*)d_in[19];
    const float* g1       = (const float*)d_in[20];
    const float* beta1    = (const float*)d_in[21];
    float* out = (float*)d_out;

    char* ws = (char*)d_ws;
    size_t off = 0;
    auto alloc = [&](size_t bytes) -> void* {
        void* p = ws + off;
        off += (bytes + 255) & ~(size_t)255;
        return p;
    };
    unsigned* xlp  = (unsigned*)alloc((size_t)NN * 64 * 4);   // x_l packed f16x2
    unsigned* xrp  = (unsigned*)alloc((size_t)NN * 64 * 4);   // x_r packed f16x2
    float* ident   = (float*)alloc((size_t)NN * 128 * 4);
    int* deg       = (int*)alloc((size_t)NN * 4);
    int* row_start = (int*)alloc((size_t)(NN + 1) * 4);
    int* rank      = (int*)alloc((size_t)NE * 4);
    int* bsum      = (int*)alloc((size_t)(NB + 1) * 4);
    int2* csr_es   = (int2*)alloc((size_t)NE * 8);
    unsigned* gatp = (unsigned*)alloc((size_t)NN * 64 * 4);   // gat packed bf16x2
    unsigned short* Wtl   = (unsigned short*)alloc(8192 * 2);
    unsigned short* Wtr   = (unsigned short*)alloc(8192 * 2);
    unsigned short* Wtres = (unsigned short*)alloc(8192 * 2);
    unsigned short* Wt0   = (unsigned short*)alloc(24576 * 2);
    unsigned short* Wt1   = (unsigned short*)alloc(16384 * 2);
    unsigned* Wep = (unsigned*)alloc(1024 * 4);
    unsigned* efp = (unsigned*)alloc((size_t)NE * 8 * 4);

    k0_prep<<<NB, 256, 0, stream>>>(W_l, W_r, res_W, W0, W1, W_e,
                                    Wtl, Wtr, Wtres, Wt0, Wt1, Wep,
                                    deg, row_start);

    ka_nodes_degree<<<K1B + (NE + 255) / 256, 256, 0, stream>>>(
        nf, Wtl, b_l, Wtr, b_r, Wtres, res_b, res_g, res_beta,
        xlp, xrp, ident, eidx, deg, rank, ef, efp);

    k3a_blocksum<<<NB, 256, 0, stream>>>(deg, bsum);
    k3c_apply<<<NB, 256, 0, stream>>>(deg, bsum, row_start);

    k4_scatter<<<(NE + 255) / 256, 256, 0, stream>>>(eidx, row_start, rank, csr_es);

    k5_attn_aggregate<<<(NN * 64 + 255) / 256, 256, 0, stream>>>(
        csr_es, row_start, efp, Wep, att, xlp, xrp, gat_bias, gatp);

    k6_mlp_mfma<<<(NN + 63) / 64, 256, 0, stream>>>(
        nf, gatp, ident, Wt0, b0, g0, beta0, Wt1, b1, g1, beta1, out);
}